// Round 1
// baseline (3042.683 us; speedup 1.0000x reference)
//
#include <hip/hip_runtime.h>
#include <math.h>

#define D_IN 32
#define NH 4
#define DH 8

// ---------------------------------------------------------------- K1: QKV
__global__ void qkv_kernel(const float* __restrict__ x,
                           const float* __restrict__ Wq,
                           const float* __restrict__ Wk,
                           const float* __restrict__ Wv,
                           float* __restrict__ q,
                           float* __restrict__ k,
                           float* __restrict__ v,
                           int N) {
    __shared__ float sWq[1024], sWk[1024], sWv[1024];
    for (int i = threadIdx.x; i < 1024; i += blockDim.x) {
        sWq[i] = Wq[i];
        sWk[i] = Wk[i];
        sWv[i] = Wv[i];
    }
    __syncthreads();
    int n = blockIdx.x * blockDim.x + threadIdx.x;
    if (n >= N) return;

    float xr[32];
    const float4* x4 = (const float4*)(x + (size_t)n * 32);
    #pragma unroll
    for (int i = 0; i < 8; i++) {
        float4 f = x4[i];
        xr[4*i+0] = f.x; xr[4*i+1] = f.y; xr[4*i+2] = f.z; xr[4*i+3] = f.w;
    }

    const float scale = 0.35355339059327373f; // 1/sqrt(D_HEAD)
    float acc[32];

    // q (pre-scaled by 1/sqrt(8) so edge kernels skip the multiply)
    #pragma unroll
    for (int j = 0; j < 32; j++) acc[j] = 0.f;
    for (int i = 0; i < 32; i++) {
        float xi = xr[i];
        #pragma unroll
        for (int j = 0; j < 32; j++) acc[j] += xi * sWq[i*32 + j];
    }
    {
        float4* o4 = (float4*)(q + (size_t)n * 32);
        #pragma unroll
        for (int i = 0; i < 8; i++)
            o4[i] = make_float4(acc[4*i]*scale, acc[4*i+1]*scale, acc[4*i+2]*scale, acc[4*i+3]*scale);
    }

    // k
    #pragma unroll
    for (int j = 0; j < 32; j++) acc[j] = 0.f;
    for (int i = 0; i < 32; i++) {
        float xi = xr[i];
        #pragma unroll
        for (int j = 0; j < 32; j++) acc[j] += xi * sWk[i*32 + j];
    }
    {
        float4* o4 = (float4*)(k + (size_t)n * 32);
        #pragma unroll
        for (int i = 0; i < 8; i++)
            o4[i] = make_float4(acc[4*i], acc[4*i+1], acc[4*i+2], acc[4*i+3]);
    }

    // v
    #pragma unroll
    for (int j = 0; j < 32; j++) acc[j] = 0.f;
    for (int i = 0; i < 32; i++) {
        float xi = xr[i];
        #pragma unroll
        for (int j = 0; j < 32; j++) acc[j] += xi * sWv[i*32 + j];
    }
    {
        float4* o4 = (float4*)(v + (size_t)n * 32);
        #pragma unroll
        for (int i = 0; i < 8; i++)
            o4[i] = make_float4(acc[4*i], acc[4*i+1], acc[4*i+2], acc[4*i+3]);
    }
}

// order-preserving float -> uint encoding (monotonic), enc(finite) > 0
__device__ __forceinline__ unsigned enc_f32(float f) {
    unsigned u = __float_as_uint(f);
    return (u & 0x80000000u) ? ~u : (u | 0x80000000u);
}
__device__ __forceinline__ float dec_f32(unsigned u) {
    return (u & 0x80000000u) ? __uint_as_float(u & 0x7fffffffu)
                             : __uint_as_float(~u);
}

// ------------------------------------------------- K2: edge scores + seg-max
__global__ void score_max_kernel(const float* __restrict__ q,
                                 const float* __restrict__ k,
                                 const int* __restrict__ src,
                                 const int* __restrict__ dst,
                                 unsigned* __restrict__ menc,
                                 int EH) {
    int tid = blockIdx.x * blockDim.x + threadIdx.x;
    if (tid >= EH) return;
    int e = tid >> 2;
    int h = tid & 3;
    int s = src[e];
    int d = dst[e];
    const float4* q4 = (const float4*)q;
    const float4* k4 = (const float4*)k;
    float4 qa = q4[(size_t)d*8 + h*2], qb = q4[(size_t)d*8 + h*2 + 1];
    float4 ka = k4[(size_t)s*8 + h*2], kb = k4[(size_t)s*8 + h*2 + 1];
    float sc = qa.x*ka.x + qa.y*ka.y + qa.z*ka.z + qa.w*ka.w
             + qb.x*kb.x + qb.y*kb.y + qb.z*kb.z + qb.w*kb.w;
    atomicMax(&menc[(size_t)d*4 + h], enc_f32(sc));
}

// -------------------------------------- K3: exp, denom + weighted-V scatter
__global__ void edge_accum_kernel(const float* __restrict__ q,
                                  const float* __restrict__ k,
                                  const float* __restrict__ v,
                                  const int* __restrict__ src,
                                  const int* __restrict__ dst,
                                  const unsigned* __restrict__ menc,
                                  float* __restrict__ denom,
                                  float* __restrict__ msg,
                                  int EH) {
    int tid = blockIdx.x * blockDim.x + threadIdx.x;
    if (tid >= EH) return;
    int e = tid >> 2;
    int h = tid & 3;
    int s = src[e];
    int d = dst[e];
    const float4* q4 = (const float4*)q;
    const float4* k4 = (const float4*)k;
    float4 qa = q4[(size_t)d*8 + h*2], qb = q4[(size_t)d*8 + h*2 + 1];
    float4 ka = k4[(size_t)s*8 + h*2], kb = k4[(size_t)s*8 + h*2 + 1];
    float sc = qa.x*ka.x + qa.y*ka.y + qa.z*ka.z + qa.w*ka.w
             + qb.x*kb.x + qb.y*kb.y + qb.z*kb.z + qb.w*kb.w;

    unsigned u = menc[(size_t)d*4 + h];
    float m = (u == 0u) ? 0.f : dec_f32(u);
    float w = __expf(sc - m);

    atomicAdd(&denom[(size_t)d*4 + h], w);

    const float4* v4 = (const float4*)v;
    float4 va = v4[(size_t)s*8 + h*2], vb = v4[(size_t)s*8 + h*2 + 1];
    float* mrow = msg + (size_t)d*32 + h*8;
    atomicAdd(mrow + 0, w * va.x);
    atomicAdd(mrow + 1, w * va.y);
    atomicAdd(mrow + 2, w * va.z);
    atomicAdd(mrow + 3, w * va.w);
    atomicAdd(mrow + 4, w * vb.x);
    atomicAdd(mrow + 5, w * vb.y);
    atomicAdd(mrow + 6, w * vb.z);
    atomicAdd(mrow + 7, w * vb.w);
}

// ---------------------------------------------- K4: (msg/denom)@Wo + resid
__global__ void out_kernel(const float* __restrict__ x,
                           const float* __restrict__ msg,
                           const float* __restrict__ denom,
                           const float* __restrict__ Wo,
                           float* __restrict__ out,
                           int N) {
    __shared__ float sWo[1024];
    for (int i = threadIdx.x; i < 1024; i += blockDim.x) sWo[i] = Wo[i];
    __syncthreads();
    int n = blockIdx.x * blockDim.x + threadIdx.x;
    if (n >= N) return;

    float dn[4];
    #pragma unroll
    for (int h = 0; h < 4; h++)
        dn[h] = 1.0f / fmaxf(denom[(size_t)n*4 + h], 1e-16f);

    float a[32];
    const float4* m4 = (const float4*)(msg + (size_t)n * 32);
    #pragma unroll
    for (int i = 0; i < 8; i++) {
        float4 f = m4[i];
        float s = dn[i >> 1];
        a[4*i+0] = f.x * s; a[4*i+1] = f.y * s; a[4*i+2] = f.z * s; a[4*i+3] = f.w * s;
    }

    float acc[32];
    #pragma unroll
    for (int j = 0; j < 32; j++) acc[j] = 0.f;
    for (int i = 0; i < 32; i++) {
        float ai = a[i];
        #pragma unroll
        for (int j = 0; j < 32; j++) acc[j] += ai * sWo[i*32 + j];
    }

    const float4* x4 = (const float4*)(x + (size_t)n * 32);
    float4* o4 = (float4*)(out + (size_t)n * 32);
    #pragma unroll
    for (int i = 0; i < 8; i++) {
        float4 xv = x4[i];
        o4[i] = make_float4(xv.x + acc[4*i+0], xv.y + acc[4*i+1],
                            xv.z + acc[4*i+2], xv.w + acc[4*i+3]);
    }
}

extern "C" void kernel_launch(void* const* d_in, const int* in_sizes, int n_in,
                              void* d_out, int out_size, void* d_ws, size_t ws_size,
                              hipStream_t stream) {
    const float* x  = (const float*)d_in[0];
    const float* Wq = (const float*)d_in[1];
    const float* Wk = (const float*)d_in[2];
    const float* Wv = (const float*)d_in[3];
    const float* Wo = (const float*)d_in[4];
    const int*   ei = (const int*)d_in[5];   // int32 (JAX x64 disabled)

    const int N = in_sizes[0] / D_IN;
    const int E = in_sizes[5] / 2;
    const int* src = ei;        // edge_index[0]
    const int* dst = ei + E;    // edge_index[1]

    // workspace layout (fp32):
    //   q[N*32] k[N*32] v[N*32] menc[N*4 uint] denom[N*4] msg[N*32]
    float*    q     = (float*)d_ws;
    float*    k     = q + (size_t)N * 32;
    float*    v     = k + (size_t)N * 32;
    unsigned* menc  = (unsigned*)(v + (size_t)N * 32);
    float*    denom = (float*)(menc + (size_t)N * 4);
    float*    msg   = denom + (size_t)N * 4;

    hipMemsetAsync(menc,  0, (size_t)N * 4 * sizeof(unsigned), stream);
    hipMemsetAsync(denom, 0, (size_t)N * 4 * sizeof(float), stream);
    hipMemsetAsync(msg,   0, (size_t)N * 32 * sizeof(float), stream);

    qkv_kernel<<<(N + 255) / 256, 256, 0, stream>>>(x, Wq, Wk, Wv, q, k, v, N);

    const int EH = E * NH;
    score_max_kernel<<<(EH + 255) / 256, 256, 0, stream>>>(q, k, src, dst, menc, EH);
    edge_accum_kernel<<<(EH + 255) / 256, 256, 0, stream>>>(q, k, v, src, dst, menc,
                                                            denom, msg, EH);
    out_kernel<<<(N + 255) / 256, 256, 0, stream>>>(x, msg, denom, Wo,
                                                    (float*)d_out, N);
}

// Round 2
// 566.438 us; speedup vs baseline: 5.3716x; 5.3716x over previous
//
#include <hip/hip_runtime.h>
#include <math.h>

#define D_IN 32
#define NH 4
#define DH 8

// ---------------------------------------------------------------- K1: QKV
__global__ void qkv_kernel(const float* __restrict__ x,
                           const float* __restrict__ Wq,
                           const float* __restrict__ Wk,
                           const float* __restrict__ Wv,
                           float* __restrict__ q,
                           float* __restrict__ k,
                           float* __restrict__ v,
                           int N) {
    __shared__ float sWq[1024], sWk[1024], sWv[1024];
    for (int i = threadIdx.x; i < 1024; i += blockDim.x) {
        sWq[i] = Wq[i];
        sWk[i] = Wk[i];
        sWv[i] = Wv[i];
    }
    __syncthreads();
    int n = blockIdx.x * blockDim.x + threadIdx.x;
    if (n >= N) return;

    float xr[32];
    const float4* x4 = (const float4*)(x + (size_t)n * 32);
    #pragma unroll
    for (int i = 0; i < 8; i++) {
        float4 f = x4[i];
        xr[4*i+0] = f.x; xr[4*i+1] = f.y; xr[4*i+2] = f.z; xr[4*i+3] = f.w;
    }

    const float scale = 0.35355339059327373f; // 1/sqrt(D_HEAD)
    float acc[32];

    // q (pre-scaled by 1/sqrt(8))
    #pragma unroll
    for (int j = 0; j < 32; j++) acc[j] = 0.f;
    for (int i = 0; i < 32; i++) {
        float xi = xr[i];
        #pragma unroll
        for (int j = 0; j < 32; j++) acc[j] += xi * sWq[i*32 + j];
    }
    {
        float4* o4 = (float4*)(q + (size_t)n * 32);
        #pragma unroll
        for (int i = 0; i < 8; i++)
            o4[i] = make_float4(acc[4*i]*scale, acc[4*i+1]*scale, acc[4*i+2]*scale, acc[4*i+3]*scale);
    }

    // k
    #pragma unroll
    for (int j = 0; j < 32; j++) acc[j] = 0.f;
    for (int i = 0; i < 32; i++) {
        float xi = xr[i];
        #pragma unroll
        for (int j = 0; j < 32; j++) acc[j] += xi * sWk[i*32 + j];
    }
    {
        float4* o4 = (float4*)(k + (size_t)n * 32);
        #pragma unroll
        for (int i = 0; i < 8; i++)
            o4[i] = make_float4(acc[4*i], acc[4*i+1], acc[4*i+2], acc[4*i+3]);
    }

    // v
    #pragma unroll
    for (int j = 0; j < 32; j++) acc[j] = 0.f;
    for (int i = 0; i < 32; i++) {
        float xi = xr[i];
        #pragma unroll
        for (int j = 0; j < 32; j++) acc[j] += xi * sWv[i*32 + j];
    }
    {
        float4* o4 = (float4*)(v + (size_t)n * 32);
        #pragma unroll
        for (int i = 0; i < 8; i++)
            o4[i] = make_float4(acc[4*i], acc[4*i+1], acc[4*i+2], acc[4*i+3]);
    }
}

// ------------------------------------------------------- K2: degree histogram
__global__ void hist_kernel(const int* __restrict__ dst, int* __restrict__ deg, int E) {
    int e = blockIdx.x * blockDim.x + threadIdx.x;
    if (e < E) atomicAdd(&deg[dst[e]], 1);
}

// ------------------------------------------------ K3a: per-chunk (1024) scan
__global__ void scan1_kernel(const int4* __restrict__ deg4,
                             int4* __restrict__ off4,
                             int* __restrict__ bsum) {
    __shared__ int sh[256];
    int t = threadIdx.x;
    int idx = blockIdx.x * 256 + t;
    int4 v = deg4[idx];
    int tsum = v.x + v.y + v.z + v.w;
    sh[t] = tsum;
    __syncthreads();
    int incl = tsum;
    for (int o = 1; o < 256; o <<= 1) {
        int u = (t >= o) ? sh[t - o] : 0;
        __syncthreads();
        incl += u;
        sh[t] = incl;
        __syncthreads();
    }
    int excl = incl - tsum;
    off4[idx] = make_int4(excl, excl + v.x, excl + v.x + v.y, excl + v.x + v.y + v.z);
    if (t == 255) bsum[blockIdx.x] = incl;
}

// -------------------------------------------- K3b: scan of block sums (<=128)
__global__ void scan2_kernel(int* __restrict__ bsum, int nb) {
    __shared__ int sh[128];
    int t = threadIdx.x;
    int v = (t < nb) ? bsum[t] : 0;
    sh[t] = v;
    __syncthreads();
    int incl = v;
    for (int o = 1; o < 128; o <<= 1) {
        int u = (t >= o) ? sh[t - o] : 0;
        __syncthreads();
        incl += u;
        sh[t] = incl;
        __syncthreads();
    }
    if (t < nb) bsum[t] = incl - v;  // exclusive
}

// --------------------------------------------------- K3c: add block offsets
__global__ void scan3_kernel(int4* __restrict__ off4, const int* __restrict__ bsum) {
    int add = bsum[blockIdx.x];
    int idx = blockIdx.x * 256 + threadIdx.x;
    int4 v = off4[idx];
    off4[idx] = make_int4(v.x + add, v.y + add, v.z + add, v.w + add);
}

// --------------------------------------------- K4: scatter edges into buckets
__global__ void scatter_kernel(const int* __restrict__ src,
                               const int* __restrict__ dst,
                               int* __restrict__ cur,
                               int* __restrict__ ssrc,
                               int E) {
    int e = blockIdx.x * blockDim.x + threadIdx.x;
    if (e < E) {
        int pos = atomicAdd(&cur[dst[e]], 1);
        ssrc[pos] = src[e];
    }
}

// ------------- K5: per-node online softmax + weighted sum + @Wo + residual
// One wave per node. lane = slot*4 + h; 16 edge slots x 4 heads.
__global__ __launch_bounds__(256) void node_kernel(const float* __restrict__ q,
                                                   const float* __restrict__ k,
                                                   const float* __restrict__ v,
                                                   const int* __restrict__ off,
                                                   const int* __restrict__ ssrc,
                                                   const float* __restrict__ x,
                                                   const float* __restrict__ Wo,
                                                   float* __restrict__ out,
                                                   int N) {
    __shared__ float sWo[1024];
    __shared__ float sAttn[4][32];
    for (int i = threadIdx.x; i < 1024; i += 256) sWo[i] = Wo[i];
    __syncthreads();

    int wid  = threadIdx.x >> 6;
    int lane = threadIdx.x & 63;
    int n = blockIdx.x * 4 + wid;

    if (n < N) {
        int h    = lane & 3;
        int slot = lane >> 2;
        int e0 = off[n], e1 = off[n + 1];

        const float4* q4 = (const float4*)(q + (size_t)n * 32 + h * 8);
        float4 qa = q4[0], qb = q4[1];

        float m = -INFINITY, d = 0.f;
        float msg[8];
        #pragma unroll
        for (int j = 0; j < 8; j++) msg[j] = 0.f;

        for (int base = e0; base < e1; base += 16) {
            int e = base + slot;
            if (e < e1) {
                int s = ssrc[e];
                const float4* k4 = (const float4*)(k + (size_t)s * 32 + h * 8);
                float4 ka = k4[0], kb = k4[1];
                float sc = qa.x*ka.x + qa.y*ka.y + qa.z*ka.z + qa.w*ka.w
                         + qb.x*kb.x + qb.y*kb.y + qb.z*kb.z + qb.w*kb.w;
                const float4* v4 = (const float4*)(v + (size_t)s * 32 + h * 8);
                float4 va = v4[0], vb = v4[1];

                float mn = fmaxf(m, sc);
                float c  = __expf(m - mn);   // m==-inf -> 0
                float w  = __expf(sc - mn);
                d = d * c + w;
                msg[0] = msg[0]*c + w*va.x;
                msg[1] = msg[1]*c + w*va.y;
                msg[2] = msg[2]*c + w*va.z;
                msg[3] = msg[3]*c + w*va.w;
                msg[4] = msg[4]*c + w*vb.x;
                msg[5] = msg[5]*c + w*vb.y;
                msg[6] = msg[6]*c + w*vb.z;
                msg[7] = msg[7]*c + w*vb.w;
                m = mn;
            }
        }

        // combine the 16 slots of each head (lanes stride 4): xor 4,8,16,32
        #pragma unroll
        for (int mask = 4; mask < 64; mask <<= 1) {
            float m2 = __shfl_xor(m, mask);
            float d2 = __shfl_xor(d, mask);
            float msg2[8];
            #pragma unroll
            for (int j = 0; j < 8; j++) msg2[j] = __shfl_xor(msg[j], mask);
            float M  = fmaxf(m, m2);
            float c1 = (m  == -INFINITY) ? 0.f : __expf(m  - M);
            float c2 = (m2 == -INFINITY) ? 0.f : __expf(m2 - M);
            d = d * c1 + d2 * c2;
            #pragma unroll
            for (int j = 0; j < 8; j++) msg[j] = msg[j]*c1 + msg2[j]*c2;
            m = M;
        }

        float inv = 1.0f / fmaxf(d, 1e-16f);
        if (slot == 0) {
            #pragma unroll
            for (int j = 0; j < 8; j++) sAttn[wid][h * 8 + j] = msg[j] * inv;
        }
    }

    __syncthreads();

    if (n < N && lane < 32) {
        float acc = x[(size_t)n * 32 + lane];
        #pragma unroll
        for (int i = 0; i < 32; i++) acc += sAttn[wid][i] * sWo[i * 32 + lane];
        out[(size_t)n * 32 + lane] = acc;
    }
}

extern "C" void kernel_launch(void* const* d_in, const int* in_sizes, int n_in,
                              void* d_out, int out_size, void* d_ws, size_t ws_size,
                              hipStream_t stream) {
    const float* x  = (const float*)d_in[0];
    const float* Wq = (const float*)d_in[1];
    const float* Wk = (const float*)d_in[2];
    const float* Wv = (const float*)d_in[3];
    const float* Wo = (const float*)d_in[4];
    const int*   ei = (const int*)d_in[5];   // int32

    const int N = in_sizes[0] / D_IN;
    const int E = in_sizes[5] / 2;
    const int* src = ei;        // edge_index[0]
    const int* dst = ei + E;    // edge_index[1]

    const int NB1  = (N + 1024) / 1024;   // ensures NPAD >= N+1
    const int NPAD = NB1 * 1024;

    // workspace layout
    float* q    = (float*)d_ws;
    float* k    = q + (size_t)N * 32;
    float* v    = k + (size_t)N * 32;
    int*   deg  = (int*)(v + (size_t)N * 32);   // NPAD ints (zero-padded)
    int*   off  = deg + NPAD;                    // NPAD ints (off[N] valid)
    int*   cur  = off + NPAD;                    // N ints
    int*   bsum = cur + N;                       // NB1 ints (<=128)
    int*   ssrc = bsum + 128;                    // E ints

    hipMemsetAsync(deg, 0, (size_t)NPAD * sizeof(int), stream);

    qkv_kernel<<<(N + 255) / 256, 256, 0, stream>>>(x, Wq, Wk, Wv, q, k, v, N);

    hist_kernel<<<(E + 255) / 256, 256, 0, stream>>>(dst, deg, E);

    scan1_kernel<<<NB1, 256, 0, stream>>>((const int4*)deg, (int4*)off, bsum);
    scan2_kernel<<<1, 128, 0, stream>>>(bsum, NB1);
    scan3_kernel<<<NB1, 256, 0, stream>>>((int4*)off, bsum);

    hipMemcpyAsync(cur, off, (size_t)N * sizeof(int), hipMemcpyDeviceToDevice, stream);

    scatter_kernel<<<(E + 255) / 256, 256, 0, stream>>>(src, dst, cur, ssrc, E);

    node_kernel<<<(N + 3) / 4, 256, 0, stream>>>(q, k, v, off, ssrc, x, Wo,
                                                 (float*)d_out, N);
}

// Round 3
// 216.236 us; speedup vs baseline: 14.0711x; 2.6195x over previous
//
#include <hip/hip_runtime.h>
#include <hip/hip_fp16.h>
#include <math.h>

#define D_IN 32
#define NH 4
#define DH 8

#define BUCKET_BITS 8          // 256 nodes per bucket
#define CHUNK 8192             // edges per partition block

typedef __attribute__((ext_vector_type(8))) _Float16 half8;

// ---------------------------------------------------------------- K1: QKV
// q fp32 (pre-scaled by 1/sqrt(8)), k/v fp16
__global__ void qkv_kernel(const float* __restrict__ x,
                           const float* __restrict__ Wq,
                           const float* __restrict__ Wk,
                           const float* __restrict__ Wv,
                           float* __restrict__ q,
                           _Float16* __restrict__ kh,
                           _Float16* __restrict__ vh,
                           int N) {
    __shared__ float sWq[1024], sWk[1024], sWv[1024];
    for (int i = threadIdx.x; i < 1024; i += blockDim.x) {
        sWq[i] = Wq[i];
        sWk[i] = Wk[i];
        sWv[i] = Wv[i];
    }
    __syncthreads();
    int n = blockIdx.x * blockDim.x + threadIdx.x;
    if (n >= N) return;

    float xr[32];
    const float4* x4 = (const float4*)(x + (size_t)n * 32);
    #pragma unroll
    for (int i = 0; i < 8; i++) {
        float4 f = x4[i];
        xr[4*i+0] = f.x; xr[4*i+1] = f.y; xr[4*i+2] = f.z; xr[4*i+3] = f.w;
    }

    const float scale = 0.35355339059327373f; // 1/sqrt(D_HEAD)
    float acc[32];

    // q
    #pragma unroll
    for (int j = 0; j < 32; j++) acc[j] = 0.f;
    for (int i = 0; i < 32; i++) {
        float xi = xr[i];
        #pragma unroll
        for (int j = 0; j < 32; j++) acc[j] += xi * sWq[i*32 + j];
    }
    {
        float4* o4 = (float4*)(q + (size_t)n * 32);
        #pragma unroll
        for (int i = 0; i < 8; i++)
            o4[i] = make_float4(acc[4*i]*scale, acc[4*i+1]*scale, acc[4*i+2]*scale, acc[4*i+3]*scale);
    }

    // k -> fp16
    #pragma unroll
    for (int j = 0; j < 32; j++) acc[j] = 0.f;
    for (int i = 0; i < 32; i++) {
        float xi = xr[i];
        #pragma unroll
        for (int j = 0; j < 32; j++) acc[j] += xi * sWk[i*32 + j];
    }
    {
        _Float16* o = kh + (size_t)n * 32;
        #pragma unroll
        for (int i = 0; i < 4; i++) {
            half8 hv;
            #pragma unroll
            for (int j = 0; j < 8; j++) hv[j] = (_Float16)acc[i*8 + j];
            *(half8*)(o + i*8) = hv;
        }
    }

    // v -> fp16
    #pragma unroll
    for (int j = 0; j < 32; j++) acc[j] = 0.f;
    for (int i = 0; i < 32; i++) {
        float xi = xr[i];
        #pragma unroll
        for (int j = 0; j < 32; j++) acc[j] += xi * sWv[i*32 + j];
    }
    {
        _Float16* o = vh + (size_t)n * 32;
        #pragma unroll
        for (int i = 0; i < 4; i++) {
            half8 hv;
            #pragma unroll
            for (int j = 0; j < 8; j++) hv[j] = (_Float16)acc[i*8 + j];
            *(half8*)(o + i*8) = hv;
        }
    }
}

// ------------------------------------- K2a: coarse per-(bucket,block) counts
__global__ void coarse_hist_kernel(const int* __restrict__ dst,
                                   int* __restrict__ counts,
                                   int E, int nbuckets, int nblocks) {
    __shared__ int h[512];
    for (int i = threadIdx.x; i < nbuckets; i += 256) h[i] = 0;
    __syncthreads();
    int base = blockIdx.x * CHUNK;
    int end = min(base + CHUNK, E);
    for (int e = base + threadIdx.x; e < end; e += 256)
        atomicAdd(&h[dst[e] >> BUCKET_BITS], 1);
    __syncthreads();
    for (int i = threadIdx.x; i < nbuckets; i += 256)
        counts[(size_t)i * nblocks + blockIdx.x] = h[i];
}

// ------------------------------------------------ K3a: per-chunk (1024) scan
__global__ void scan1_kernel(const int4* __restrict__ in4,
                             int4* __restrict__ out4,
                             int* __restrict__ bsum) {
    __shared__ int sh[256];
    int t = threadIdx.x;
    int idx = blockIdx.x * 256 + t;
    int4 v = in4[idx];
    int tsum = v.x + v.y + v.z + v.w;
    sh[t] = tsum;
    __syncthreads();
    int incl = tsum;
    for (int o = 1; o < 256; o <<= 1) {
        int u = (t >= o) ? sh[t - o] : 0;
        __syncthreads();
        incl += u;
        sh[t] = incl;
        __syncthreads();
    }
    int excl = incl - tsum;
    out4[idx] = make_int4(excl, excl + v.x, excl + v.x + v.y, excl + v.x + v.y + v.z);
    if (t == 255) bsum[blockIdx.x] = incl;
}

// ------------------------------------------- K3b: scan of block sums (<=512)
__global__ void scan2_kernel(int* __restrict__ bsum, int nb) {
    __shared__ int sh[512];
    int t = threadIdx.x;
    int v = (t < nb) ? bsum[t] : 0;
    sh[t] = v;
    __syncthreads();
    int incl = v;
    for (int o = 1; o < 512; o <<= 1) {
        int u = (t >= o) ? sh[t - o] : 0;
        __syncthreads();
        incl += u;
        sh[t] = incl;
        __syncthreads();
    }
    if (t < nb) bsum[t] = incl - v;  // exclusive
}

// --------------------------------------------------- K3c: add block offsets
__global__ void scan3_kernel(int4* __restrict__ out4, const int* __restrict__ bsum) {
    int add = bsum[blockIdx.x];
    int idx = blockIdx.x * 256 + threadIdx.x;
    int4 v = out4[idx];
    out4[idx] = make_int4(v.x + add, v.y + add, v.z + add, v.w + add);
}

// ----------------------------------- K4: partition edges into coarse buckets
__global__ void partition_kernel(const int* __restrict__ src,
                                 const int* __restrict__ dst,
                                 const int* __restrict__ base,
                                 unsigned* __restrict__ packed,
                                 int E, int nbuckets, int nblocks) {
    __shared__ int cur[512];
    for (int i = threadIdx.x; i < nbuckets; i += 256) cur[i] = 0;
    __syncthreads();
    int b0 = blockIdx.x * CHUNK;
    int end = min(b0 + CHUNK, E);
    for (int e = b0 + threadIdx.x; e < end; e += 256) {
        int d = dst[e];
        int bkt = d >> BUCKET_BITS;
        int r = atomicAdd(&cur[bkt], 1);
        int pos = base[(size_t)bkt * nblocks + blockIdx.x] + r;
        packed[pos] = (unsigned)src[e] | ((unsigned)(d & 255) << 20);
    }
}

// --------------- K5: fine sort within bucket + exact node offsets (off[])
__global__ void fine_kernel(const unsigned* __restrict__ packed,
                            const int* __restrict__ base,
                            int* __restrict__ off,
                            int* __restrict__ ssrc,
                            int E, int nbuckets, int nblocks) {
    __shared__ int hist[256];
    __shared__ int sc[256];
    __shared__ int excl[256];
    int b = blockIdx.x;
    int t = threadIdx.x;
    int bstart = base[(size_t)b * nblocks];
    int bend = (b + 1 < nbuckets) ? base[(size_t)(b + 1) * nblocks] : E;

    hist[t] = 0;
    __syncthreads();
    for (int e = bstart + t; e < bend; e += 256)
        atomicAdd(&hist[packed[e] >> 20], 1);
    __syncthreads();

    // exclusive scan of hist (256 elements)
    int vt = hist[t];
    sc[t] = vt;
    __syncthreads();
    int incl = vt;
    for (int o = 1; o < 256; o <<= 1) {
        int u = (t >= o) ? sc[t - o] : 0;
        __syncthreads();
        incl += u;
        sc[t] = incl;
        __syncthreads();
    }
    excl[t] = incl - vt;
    off[b * 256 + t] = bstart + incl - vt;

    hist[t] = 0;  // reuse as cursor
    __syncthreads();

    for (int e = bstart + t; e < bend; e += 256) {
        unsigned p = packed[e];
        int local = p >> 20;
        int r = atomicAdd(&hist[local], 1);
        ssrc[bstart + excl[local] + r] = (int)(p & 0xFFFFFu);
    }
}

// ------------- K6: per-node online softmax + weighted sum + @Wo + residual
// One wave per node. lane = slot*4 + h; 16 edge slots x 4 heads.
__global__ __launch_bounds__(256) void node_kernel(const float* __restrict__ q,
                                                   const _Float16* __restrict__ kh,
                                                   const _Float16* __restrict__ vh,
                                                   const int* __restrict__ off,
                                                   const int* __restrict__ ssrc,
                                                   const float* __restrict__ x,
                                                   const float* __restrict__ Wo,
                                                   float* __restrict__ out,
                                                   int N) {
    __shared__ float sWo[1024];
    __shared__ float sAttn[4][32];
    for (int i = threadIdx.x; i < 1024; i += 256) sWo[i] = Wo[i];
    __syncthreads();

    int wid  = threadIdx.x >> 6;
    int lane = threadIdx.x & 63;
    int n = blockIdx.x * 4 + wid;

    if (n < N) {
        int h    = lane & 3;
        int slot = lane >> 2;
        int e0 = off[n], e1 = off[n + 1];

        const float4* q4 = (const float4*)(q + (size_t)n * 32 + h * 8);
        float4 qa = q4[0], qb = q4[1];

        float m = -INFINITY, d = 0.f;
        float msg[8];
        #pragma unroll
        for (int j = 0; j < 8; j++) msg[j] = 0.f;

        for (int base = e0; base < e1; base += 16) {
            int e = base + slot;
            if (e < e1) {
                int s = ssrc[e];
                half8 ka = *(const half8*)(kh + ((size_t)s << 5) + (h << 3));
                float sc = qa.x*(float)ka[0] + qa.y*(float)ka[1]
                         + qa.z*(float)ka[2] + qa.w*(float)ka[3]
                         + qb.x*(float)ka[4] + qb.y*(float)ka[5]
                         + qb.z*(float)ka[6] + qb.w*(float)ka[7];
                half8 va = *(const half8*)(vh + ((size_t)s << 5) + (h << 3));

                float mn = fmaxf(m, sc);
                float c  = __expf(m - mn);   // m==-inf -> 0
                float w  = __expf(sc - mn);
                d = d * c + w;
                #pragma unroll
                for (int j = 0; j < 8; j++)
                    msg[j] = msg[j]*c + w*(float)va[j];
                m = mn;
            }
        }

        // combine the 16 slots of each head (lanes stride 4): xor 4,8,16,32
        #pragma unroll
        for (int mask = 4; mask < 64; mask <<= 1) {
            float m2 = __shfl_xor(m, mask);
            float d2 = __shfl_xor(d, mask);
            float msg2[8];
            #pragma unroll
            for (int j = 0; j < 8; j++) msg2[j] = __shfl_xor(msg[j], mask);
            float M  = fmaxf(m, m2);
            float c1 = (m  == -INFINITY) ? 0.f : __expf(m  - M);
            float c2 = (m2 == -INFINITY) ? 0.f : __expf(m2 - M);
            d = d * c1 + d2 * c2;
            #pragma unroll
            for (int j = 0; j < 8; j++) msg[j] = msg[j]*c1 + msg2[j]*c2;
            m = M;
        }

        float inv = 1.0f / fmaxf(d, 1e-16f);
        if (slot == 0) {
            #pragma unroll
            for (int j = 0; j < 8; j++) sAttn[wid][h * 8 + j] = msg[j] * inv;
        }
    }

    __syncthreads();

    if (n < N && lane < 32) {
        float acc = x[(size_t)n * 32 + lane];
        #pragma unroll
        for (int i = 0; i < 32; i++) acc += sAttn[wid][i] * sWo[i * 32 + lane];
        out[(size_t)n * 32 + lane] = acc;
    }
}

extern "C" void kernel_launch(void* const* d_in, const int* in_sizes, int n_in,
                              void* d_out, int out_size, void* d_ws, size_t ws_size,
                              hipStream_t stream) {
    const float* x  = (const float*)d_in[0];
    const float* Wq = (const float*)d_in[1];
    const float* Wk = (const float*)d_in[2];
    const float* Wv = (const float*)d_in[3];
    const float* Wo = (const float*)d_in[4];
    const int*   ei = (const int*)d_in[5];   // int32

    const int N = in_sizes[0] / D_IN;
    const int E = in_sizes[5] / 2;
    const int* src = ei;        // edge_index[0]
    const int* dst = ei + E;    // edge_index[1]

    const int nbuckets = (N + 255) >> BUCKET_BITS;          // 391
    const int nblocks  = (E + CHUNK - 1) / CHUNK;           // 391
    const int L    = nbuckets * nblocks;
    const int NB1  = (L + 1023) / 1024;                     // scan chunks
    const int LPAD = NB1 * 1024;

    // workspace layout
    float*    q       = (float*)d_ws;
    _Float16* kh      = (_Float16*)(q + (size_t)N * 32);
    _Float16* vh      = kh + (size_t)N * 32;
    int*      scanarr = (int*)(vh + (size_t)N * 32);        // LPAD ints
    int*      bsum    = scanarr + LPAD;                     // 512 ints
    int*      off     = bsum + 512;                         // nbuckets*256+64
    unsigned* packed  = (unsigned*)(off + (size_t)nbuckets * 256 + 64);
    int*      ssrc    = (int*)(packed + (size_t)E);

    hipMemsetAsync(scanarr, 0, (size_t)LPAD * sizeof(int), stream);

    qkv_kernel<<<(N + 255) / 256, 256, 0, stream>>>(x, Wq, Wk, Wv, q, kh, vh, N);

    coarse_hist_kernel<<<nblocks, 256, 0, stream>>>(dst, scanarr, E, nbuckets, nblocks);

    scan1_kernel<<<NB1, 256, 0, stream>>>((const int4*)scanarr, (int4*)scanarr, bsum);
    scan2_kernel<<<1, 512, 0, stream>>>(bsum, NB1);
    scan3_kernel<<<NB1, 256, 0, stream>>>((int4*)scanarr, bsum);

    partition_kernel<<<nblocks, 256, 0, stream>>>(src, dst, scanarr, packed,
                                                  E, nbuckets, nblocks);

    fine_kernel<<<nbuckets, 256, 0, stream>>>(packed, scanarr, off, ssrc,
                                              E, nbuckets, nblocks);

    node_kernel<<<(N + 3) / 4, 256, 0, stream>>>(q, kh, vh, off, ssrc, x, Wo,
                                                 (float*)d_out, N);
}